// Round 14
// baseline (374.275 us; speedup 1.0000x reference)
//
#include <hip/hip_runtime.h>
#include <hip/hip_bf16.h>

// Problem constants
#define Bb 8
#define Nn 4096
#define Mm 256
#define Dd 1024
#define Hh 16
#define HDd 64
#define Ss 4352   // N + M
#define INNERd 1024
#define SPLIT 8

typedef __attribute__((ext_vector_type(4))) float f32x4;
typedef __attribute__((ext_vector_type(8))) short short8;
typedef __attribute__((ext_vector_type(4))) int int4v;

__device__ __forceinline__ float bf2f(short u) {
  union { unsigned int i; float f; } c;
  c.i = ((unsigned int)(unsigned short)u) << 16;
  return c.f;
}
__device__ __forceinline__ short f2bf(float f) {
  union { float f; unsigned int i; } c; c.f = f;
  unsigned int x = c.i;
  x += 0x7fff + ((x >> 16) & 1);   // RNE
  return (short)(x >> 16);
}
__device__ __forceinline__ void gload16(const short* g, short* l) {
  __builtin_amdgcn_global_load_lds(
      (const __attribute__((address_space(1))) void*)g,
      (__attribute__((address_space(3))) void*)l, 16, 0, 0);
}

// =====================================================================
// Fused prep: blocks [0,32768) ln(x) [B*N rows];
// [32768,34816) ln(latents) [B*M = 2048 rows];
// [34816,38912) weight convert+transpose f32->bf16 (Wq | Wkv | Wo).
// =====================================================================
__global__ __launch_bounds__(256) void prep_kernel(
    const float* __restrict__ x, const float* __restrict__ lat,
    const float* __restrict__ lnxw, const float* __restrict__ lnxb,
    const float* __restrict__ lnlw, const float* __restrict__ lnlb,
    const float* __restrict__ Wq, const float* __restrict__ Wkv,
    const float* __restrict__ Wo,
    short* __restrict__ xn, short* __restrict__ lnr,
    short* __restrict__ Wqkvt, short* __restrict__ Wot) {
  __shared__ float shbuf[32 * 33];
  int b = blockIdx.x, t = threadIdx.x;
  if (b < 34816) {
    const float *src, *w, *bv; short* dst; int row;
    if (b < 32768) { src = x;   w = lnxw; bv = lnxb; dst = xn;  row = b; }
    else           { src = lat; w = lnlw; bv = lnlb; dst = lnr; row = b - 32768; }
    const float4* x4 = (const float4*)(src + (size_t)row * Dd);
    float4 v = x4[t];
    float s  = v.x + v.y + v.z + v.w;
    float ss = v.x*v.x + v.y*v.y + v.z*v.z + v.w*v.w;
#pragma unroll
    for (int o = 1; o < 64; o <<= 1) {
      s  += __shfl_xor(s,  o, 64);
      ss += __shfl_xor(ss, o, 64);
    }
    int wv = t >> 6;
    if ((t & 63) == 0) { shbuf[wv] = s; shbuf[4 + wv] = ss; }
    __syncthreads();
    float tot  = shbuf[0] + shbuf[1] + shbuf[2] + shbuf[3];
    float tot2 = shbuf[4] + shbuf[5] + shbuf[6] + shbuf[7];
    float mean = tot * (1.0f / Dd);
    float var  = tot2 * (1.0f / Dd) - mean * mean;
    float inv  = rsqrtf(var + 1e-5f);
    float4 wv4 = ((const float4*)w)[t];
    float4 bv4 = ((const float4*)bv)[t];
    short4 o4;
    o4.x = f2bf((v.x - mean) * inv * wv4.x + bv4.x);
    o4.y = f2bf((v.y - mean) * inv * wv4.y + bv4.y);
    o4.z = f2bf((v.z - mean) * inv * wv4.z + bv4.z);
    o4.w = f2bf((v.w - mean) * inv * wv4.w + bv4.w);
    *(short4*)(dst + (size_t)row * Dd + t * 4) = o4;
  } else {
    int tb = b - 34816;
    const float* src; short* dst; int Ncol, bx, by;
    if (tb < 1024)      { src = Wq;  dst = Wqkvt; Ncol = 1024; bx = tb & 31; by = tb >> 5; }
    else if (tb < 3072) { int u = tb - 1024; src = Wkv; dst = Wqkvt + (size_t)1024 * 1024; Ncol = 2048; bx = u & 63; by = u >> 6; }
    else                { int u = tb - 3072; src = Wo;  dst = Wot; Ncol = 1024; bx = u & 31; by = u >> 5; }
    int tx = t & 31, ty = t >> 5;
#pragma unroll
    for (int i = 0; i < 32; i += 8)
      shbuf[(ty + i) * 33 + tx] = src[(size_t)(by * 32 + ty + i) * Ncol + bx * 32 + tx];
    __syncthreads();
#pragma unroll
    for (int i = 0; i < 32; i += 8)
      dst[(size_t)(bx * 32 + ty + i) * 1024 + by * 32 + tx] = f2bf(shbuf[tx * 33 + ty + i]);
  }
}

// =====================================================================
// Merged m97-structure GEMM (one dispatch, 4480 blocks):
//   blocks [0,4096):   A=xn,  Bt=Wkv^T  -> k/v scatter + fused 2D RoPE
//   blocks [4096,4480): A=lnr, Bt=[Wq|Wkv]^T -> q (scaled by 0.125*log2e)
//                       / k_l / v_l at s=N+m
// 128x128 tile, 4 waves, BK=64, ~36KB LDS -> 4 blocks/CU.
// =====================================================================
__global__ __launch_bounds__(256, 4) void gemm_fused_kernel(
    const short* __restrict__ xn, const short* __restrict__ lnr,
    const short* __restrict__ Wkvt, const short* __restrict__ Wqkvt,
    short* __restrict__ qdst, short* __restrict__ kdst, short* __restrict__ vdst) {
  __shared__ __align__(16) short Asm[128 * 64];
  __shared__ __align__(16) short Bsm[128 * 64];
  __shared__ float ctab[1024];
  int t = threadIdx.x;
  int wave = t >> 6, lane = t & 63;
  int wm = (wave >> 1) * 64, wn = (wave & 1) * 64;
  int lr = lane & 15, lg = lane >> 4;
  bool big = (int)blockIdx.x < 4096;
  const short* A  = big ? xn  : lnr;
  const short* Bt = big ? Wkvt : Wqkvt;
  int bid = big ? blockIdx.x : blockIdx.x - 4096;
  int nwg = big ? 4096 : 384;
  int ncp = big ? 16 : 24;
  int cpx = nwg >> 3;
  int swz = (bid & 7) * cpx + (bid >> 3);
  int colp = swz % ncp, rowp = swz / ncp;
  int brow = rowp * 128, bcol = colp * 128;
  if (big) {
#pragma unroll
    for (int i = t; i < 512; i += 256) {
      int pos = i >> 3, f = i & 7;
      float ang = (float)pos * exp2f(-1.6609640474436813f * (float)f);
      ctab[i] = cosf(ang);
      ctab[512 + i] = sinf(ang);
    }
  }
  f32x4 acc[4][4] = {};
  for (int kt = 0; kt < 1024; kt += 64) {
    __syncthreads();
#pragma unroll
    for (int u = 0; u < 4; u++) {
      int cid = t + u * 256;                 // 1024 16B-chunks per operand tile
      int r = cid >> 3, c = cid & 7;
      int cl = c ^ (r & 7);                  // inverse-swizzled global source
      gload16(A + (size_t)(brow + r) * 1024 + kt + cl * 8, Asm + cid * 8);
      gload16(Bt + (size_t)(bcol + r) * 1024 + kt + cl * 8, Bsm + cid * 8);
    }
    __syncthreads();                         // drains vmcnt before barrier
#pragma unroll
    for (int ks = 0; ks < 2; ks++) {
      short8 a[4], b[4];
#pragma unroll
      for (int i = 0; i < 4; i++) {
        int ra = wm + i * 16 + lr;
        a[i] = *(const short8*)(Asm + ra * 64 + (((ks * 4 + lg) ^ (ra & 7)) * 8));
        int rb = wn + i * 16 + lr;
        b[i] = *(const short8*)(Bsm + rb * 64 + (((ks * 4 + lg) ^ (rb & 7)) * 8));
      }
#pragma unroll
      for (int mi = 0; mi < 4; mi++)
#pragma unroll
        for (int ni = 0; ni < 4; ni++)
          acc[mi][ni] = __builtin_amdgcn_mfma_f32_16x16x32_bf16(a[mi], b[ni], acc[mi][ni], 0, 0, 0);
    }
  }
  // ---------------- epilogue ----------------
  int cbase = bcol + wn;                     // wave's 64-col block = one head slice
  if (big) {
    bool kreg = cbase < 1024;
    short* dstp = kreg ? kdst : vdst;
    int h = (cbase & 1023) >> 6;
#pragma unroll
    for (int mi = 0; mi < 4; mi++)
#pragma unroll
      for (int rr = 0; rr < 4; rr++) {
        int row = brow + wm + mi * 16 + lg * 4 + rr;
        int bb = row >> 12, n = row & 4095;
        float v[4];
#pragma unroll
        for (int ni = 0; ni < 4; ni++) v[ni] = acc[mi][ni][rr];
        if (kreg) {                           // fused 2D RoPE on d<32 (ni 0,1)
          int pos = (lr & 8) ? (n & 63) : (n >> 6);
          float cs = ctab[pos * 8 + (lr & 7)];
          float sn = ctab[512 + pos * 8 + (lr & 7)];
          float v0 = v[0], v1 = v[1];
          v[0] = v0 * cs - v1 * sn;
          v[1] = v1 * cs + v0 * sn;
        }
        size_t rb = (((size_t)(bb * Hh + h)) * Ss + n) * HDd;
#pragma unroll
        for (int ni = 0; ni < 4; ni++)
          dstp[rb + ni * 16 + lr] = f2bf(v[ni]);
      }
  } else {
#pragma unroll
    for (int mi = 0; mi < 4; mi++)
#pragma unroll
      for (int rr = 0; rr < 4; rr++) {
        int row = brow + wm + mi * 16 + lg * 4 + rr;
        int bb = row >> 8, m = row & 255;
        float v[4];
#pragma unroll
        for (int ni = 0; ni < 4; ni++) v[ni] = acc[mi][ni][rr];
        if (cbase < 1024) {                  // q, scaled HD^-0.5 * log2(e)
          int h = cbase >> 6;
          size_t rb = (((size_t)(bb * Hh + h)) * Mm + m) * HDd;
#pragma unroll
          for (int ni = 0; ni < 4; ni++)
            qdst[rb + ni * 16 + lr] = f2bf(v[ni] * 0.18033688f);
        } else if (cbase < 2048) {           // k_l at s = N + m
          int h = (cbase - 1024) >> 6;
          size_t rb = (((size_t)(bb * Hh + h)) * Ss + (Nn + m)) * HDd;
#pragma unroll
          for (int ni = 0; ni < 4; ni++)
            kdst[rb + ni * 16 + lr] = f2bf(v[ni]);
        } else {                             // v_l at s = N + m
          int h = (cbase - 2048) >> 6;
          size_t rb = (((size_t)(bb * Hh + h)) * Ss + (Nn + m)) * HDd;
#pragma unroll
          for (int ni = 0; ni < 4; ni++)
            vdst[rb + ni * 16 + lr] = f2bf(v[ni]);
        }
      }
  }
}

// ---------------- out projection: C[2048][1024] fp32 = aout bf16 @ Wo^T ----------------
__global__ __launch_bounds__(256, 4) void gemm_out_kernel(
    const short* __restrict__ A, const short* __restrict__ Bt,
    float* __restrict__ C, int ncp) {
  __shared__ __align__(16) short Asm[128 * 64];
  __shared__ __align__(16) short Bsm[128 * 64];
  int t = threadIdx.x;
  int wave = t >> 6, lane = t & 63;
  int wm = (wave >> 1) * 64, wn = (wave & 1) * 64;
  int lr = lane & 15, lg = lane >> 4;
  int nwg = gridDim.x;
  int cpx = nwg >> 3;
  int swz = (blockIdx.x & 7) * cpx + (blockIdx.x >> 3);
  int colp = swz % ncp, rowp = swz / ncp;
  int brow = rowp * 128, bcol = colp * 128;
  f32x4 acc[4][4] = {};
  for (int kt = 0; kt < 1024; kt += 64) {
    __syncthreads();
#pragma unroll
    for (int u = 0; u < 4; u++) {
      int cid = t + u * 256;
      int r = cid >> 3, c = cid & 7;
      int cl = c ^ (r & 7);
      gload16(A + (size_t)(brow + r) * 1024 + kt + cl * 8, Asm + cid * 8);
      gload16(Bt + (size_t)(bcol + r) * 1024 + kt + cl * 8, Bsm + cid * 8);
    }
    __syncthreads();
#pragma unroll
    for (int ks = 0; ks < 2; ks++) {
      short8 a[4], b[4];
#pragma unroll
      for (int i = 0; i < 4; i++) {
        int ra = wm + i * 16 + lr;
        a[i] = *(const short8*)(Asm + ra * 64 + (((ks * 4 + lg) ^ (ra & 7)) * 8));
        int rb = wn + i * 16 + lr;
        b[i] = *(const short8*)(Bsm + rb * 64 + (((ks * 4 + lg) ^ (rb & 7)) * 8));
      }
#pragma unroll
      for (int mi = 0; mi < 4; mi++)
#pragma unroll
        for (int ni = 0; ni < 4; ni++)
          acc[mi][ni] = __builtin_amdgcn_mfma_f32_16x16x32_bf16(a[mi], b[ni], acc[mi][ni], 0, 0, 0);
    }
  }
#pragma unroll
  for (int mi = 0; mi < 4; mi++)
#pragma unroll
    for (int ni = 0; ni < 4; ni++)
#pragma unroll
      for (int r = 0; r < 4; r++) {
        int row = brow + wm + mi * 16 + lg * 4 + r;
        int col = bcol + wn + ni * 16 + lr;
        C[(size_t)row * 1024 + col] = acc[mi][ni][r];
      }
}

// =====================================================================
// Flash attention, KV-split, NO-MAX exp2-softmax, SWAPPED QK^T.
// Round-10 sync structure (single buffer, 2 barriers/tile, full 32
// waves/CU occupancy provides implicit overlap). CHANGE: K never touches
// LDS - each wave reads its K fragments directly from global (identical
// lane math; L2 serves 7 of 8 waves). Removes 8 of ~24 LDS-pipe ops per
// wave-tile and the K-stage from the barrier-protected region. Only V
// (which needs the transpose scatter) is staged in LDS (8 KB).
// P^T stays in registers; O^T partials bf16 [d][q]; fp32 denominators.
// =====================================================================
__global__ __launch_bounds__(512) void attn_kernel(const short* __restrict__ qb,
                            const short* __restrict__ kb,
                            const short* __restrict__ vb,
                            short* __restrict__ pO,
                            float* __restrict__ pS) {
  __shared__ __align__(16) short Vsm[64 * 64];       // [d][slot], chunk^=(d&7)
  int blk = blockIdx.x;
  int sp = blk & (SPLIT - 1), bh = blk >> 3;
  int t = threadIdx.x, wave = t >> 6, lane = t & 63;
  int lr = lane & 15, lg = lane >> 4;
  int q0 = wave * 32;
  const short* qptr = qb + (size_t)bh * Mm * HDd;
  short8 qf[2][2];
#pragma unroll
  for (int qi = 0; qi < 2; qi++)
#pragma unroll
    for (int ks = 0; ks < 2; ks++)
      qf[qi][ks] = *(const short8*)(qptr + (size_t)(q0 + qi * 16 + lr) * HDd + ks * 32 + lg * 8);
  f32x4 accOT[4][2] = {};                    // [di][qi], O^T: col=q, rows=d
  float psq[2] = {0.0f, 0.0f};               // per-lane denominator partials
  const short* kbase = kb + (size_t)bh * Ss * HDd;
  const short* vbase = vb + (size_t)bh * Ss * HDd;
  int tile0 = (sp * 68) >> 3, tile1 = ((sp + 1) * 68) >> 3;
  for (int tt = tile0; tt < tile1; tt++) {
    int kt = tt * 64;
    __syncthreads();
    {
      int r = t >> 3, c = t & 7;             // 512 threads, one 16B V chunk each
      short8 vv = *(const short8*)(vbase + (size_t)(kt + r) * HDd + c * 8);
      int sc = ((r >> 5) << 2) | ((r >> 2) & 3);   // permuted slot chunk
      int sw = (((r >> 4) & 1) << 2) | (r & 3);    // slot within chunk
#pragma unroll
      for (int e = 0; e < 8; e++) {
        int d = c * 8 + e;
        Vsm[d * 64 + ((sc ^ (d & 7)) * 8) + sw] = vv[e];
      }
    }
    __syncthreads();
    // S^T = K @ Q^T  (swapped operands; K fragments direct from global/L2)
    f32x4 accST[4][2] = {};                  // [ji = k-subtile][qi]
#pragma unroll
    for (int ks = 0; ks < 2; ks++) {
      short8 ka[4];
#pragma unroll
      for (int ji = 0; ji < 4; ji++)
        ka[ji] = *(const short8*)(kbase + (size_t)(kt + ji * 16 + lr) * HDd + (ks * 4 + lg) * 8);
#pragma unroll
      for (int ji = 0; ji < 4; ji++)
#pragma unroll
        for (int qi = 0; qi < 2; qi++)
          accST[ji][qi] = __builtin_amdgcn_mfma_f32_16x16x32_bf16(ka[ji], qf[qi][ks], accST[ji][qi], 0, 0, 0);
    }
    // P^T = 2^(S^T); in-lane denominator partials; pack PV B-frags in-reg
    short8 pb[2][2];                         // [s][qi]
#pragma unroll
    for (int qi = 0; qi < 2; qi++) {
#pragma unroll
      for (int ji = 0; ji < 4; ji++)
#pragma unroll
        for (int r = 0; r < 4; r++) {
          float pv = exp2f(accST[ji][qi][r]);
          accST[ji][qi][r] = pv;
          psq[qi] += pv;
        }
#pragma unroll
      for (int s = 0; s < 2; s++)
#pragma unroll
        for (int r = 0; r < 4; r++) {
          pb[s][qi][r]     = f2bf(accST[2 * s][qi][r]);
          pb[s][qi][4 + r] = f2bf(accST[2 * s + 1][qi][r]);
        }
    }
    // O^T += V^T @ P^T
#pragma unroll
    for (int s = 0; s < 2; s++) {
      short8 va[4];
#pragma unroll
      for (int di = 0; di < 4; di++) {
        int d = di * 16 + lr;
        int ck = s * 4 + lg;
        va[di] = *(const short8*)(Vsm + d * 64 + ((ck ^ (d & 7)) * 8));
      }
#pragma unroll
      for (int di = 0; di < 4; di++)
#pragma unroll
        for (int qi = 0; qi < 2; qi++)
          accOT[di][qi] = __builtin_amdgcn_mfma_f32_16x16x32_bf16(va[di], pb[s][qi], accOT[di][qi], 0, 0, 0);
    }
  }
  // denominator: reduce across the 4 lg-groups
#pragma unroll
  for (int qi = 0; qi < 2; qi++) {
    psq[qi] += __shfl_xor(psq[qi], 16, 64);
    psq[qi] += __shfl_xor(psq[qi], 32, 64);
  }
  // write split partials: pS [q] fp32, pO bf16 transposed [d][q] per block
  size_t base = (size_t)blk * 256;
  if (lane < 16) {
#pragma unroll
    for (int qi = 0; qi < 2; qi++)
      pS[base + q0 + qi * 16 + lr] = psq[qi];
  }
  short* poB = pO + base * 64;               // blk * 16384
#pragma unroll
  for (int di = 0; di < 4; di++)
#pragma unroll
    for (int qi = 0; qi < 2; qi++)
#pragma unroll
      for (int r = 0; r < 4; r++)
        poB[(size_t)(di * 16 + lg * 4 + r) * 256 + q0 + qi * 16 + lr] = f2bf(accOT[di][qi][r]);
}

// ---------------- combine the SPLIT partials ([d][q] bf16, coalesced) ----------------
__global__ void attn_combine(const short* __restrict__ pO, const float* __restrict__ pS,
                             short* __restrict__ ob) {
  int blk = blockIdx.x;                      // 256 = bh*2 + d-half
  int bh = blk >> 1, dh = (blk & 1) << 5;    // 32 d-rows per block
  int q = threadIdx.x;                       // 256 threads = q
  float den = 0.0f;
  float acc[32] = {};
#pragma unroll
  for (int s = 0; s < SPLIT; s++) {
    size_t b2 = (size_t)(bh * SPLIT + s);
    den += pS[b2 * 256 + q];
    const short* po = pO + b2 * 16384 + (size_t)dh * 256;
#pragma unroll
    for (int d = 0; d < 32; d++) acc[d] += bf2f(po[d * 256 + q]);
  }
  float rden = 1.0f / den;
  int b = bh >> 4, h = bh & 15;
  short* dst = ob + ((size_t)(b * Mm + q)) * INNERd + h * HDd + dh;
#pragma unroll
  for (int c = 0; c < 4; c++) {
    short8 o8;
#pragma unroll
    for (int e = 0; e < 8; e++) o8[e] = f2bf(acc[c * 8 + e] * rden);
    *(short8*)(dst + c * 8) = o8;
  }
}

extern "C" void kernel_launch(void* const* d_in, const int* in_sizes, int n_in,
                              void* d_out, int out_size, void* d_ws, size_t ws_size,
                              hipStream_t stream) {
  const float* x    = (const float*)d_in[0];
  const float* lat  = (const float*)d_in[1];
  const float* lnxw = (const float*)d_in[2];
  const float* lnxb = (const float*)d_in[3];
  const float* lnlw = (const float*)d_in[4];
  const float* lnlb = (const float*)d_in[5];
  const float* Wq   = (const float*)d_in[6];
  const float* Wkv  = (const float*)d_in[7];
  const float* Wo   = (const float*)d_in[8];
  char* w = (char*)d_ws;
  const size_t MB = 1048576;
  short* Wqkvt = (short*)(w + 0 * MB);     // 6 MB: rows 0-1023 = Wq^T, 1024-3071 = Wkv^T
  short* Wot   = (short*)(w + 6 * MB);     // 2 MB
  short* xn    = (short*)(w + 8 * MB);     // 64 MB (reused as pO by attn)
  short* lnr   = (short*)(w + 72 * MB);    // 4 MB (reused as pS by attn)
  short* qbuf  = (short*)(w + 76 * MB);    // 4 MB
  short* kbuf  = (short*)(w + 80 * MB);    // 68 MB
  short* vbuf  = (short*)(w + 148 * MB);   // 68 MB
  short* aout  = (short*)(w + 216 * MB);   // 4 MB
  short* pO    = (short*)(w + 8 * MB);     // 32 MB bf16, aliases xn (dead by attn time)
  float* pS    = (float*)(w + 72 * MB);    // 1 MB, aliases lnr (dead by attn time)

  // fused prep: ln(x) [32768], ln(latents) [2048], weight converts [4096]
  prep_kernel<<<dim3(38912), dim3(256), 0, stream>>>(
      x, lat, lnxw, lnxb, lnlw, lnlb, Wq, Wkv, Wo, xn, lnr, Wqkvt, Wot);
  // merged GEMM: kv_x (+RoPE) and q+kv_l in one dispatch
  gemm_fused_kernel<<<dim3(4480), dim3(256), 0, stream>>>(
      xn, lnr, Wqkvt + (size_t)1024 * 1024, Wqkvt, qbuf, kbuf, vbuf);
  // flash attention with KV-split 8 + combine
  attn_kernel<<<dim3(Bb * Hh * SPLIT), dim3(512), 0, stream>>>(qbuf, kbuf, vbuf, pO, pS);
  attn_combine<<<dim3(256), dim3(256), 0, stream>>>(pO, pS, aout);
  // out = aout @ Wo (fp32).  grid: 16 rowp x 8 colp = 128
  gemm_out_kernel<<<dim3(128), dim3(256), 0, stream>>>(aout, Wot, (float*)d_out, 8);
}

// Round 15
// 304.030 us; speedup vs baseline: 1.2310x; 1.2310x over previous
//
#include <hip/hip_runtime.h>
#include <hip/hip_bf16.h>

// Problem constants
#define Bb 8
#define Nn 4096
#define Mm 256
#define Dd 1024
#define Hh 16
#define HDd 64
#define Ss 4352   // N + M
#define INNERd 1024
#define SPLIT 8

typedef __attribute__((ext_vector_type(4))) float f32x4;
typedef __attribute__((ext_vector_type(8))) short short8;
typedef __attribute__((ext_vector_type(4))) int int4v;

__device__ __forceinline__ float bf2f(short u) {
  union { unsigned int i; float f; } c;
  c.i = ((unsigned int)(unsigned short)u) << 16;
  return c.f;
}
__device__ __forceinline__ short f2bf(float f) {
  union { float f; unsigned int i; } c; c.f = f;
  unsigned int x = c.i;
  x += 0x7fff + ((x >> 16) & 1);   // RNE
  return (short)(x >> 16);
}
__device__ __forceinline__ void gload16(const short* g, short* l) {
  __builtin_amdgcn_global_load_lds(
      (const __attribute__((address_space(1))) void*)g,
      (__attribute__((address_space(3))) void*)l, 16, 0, 0);
}

// =====================================================================
// Fused prep: blocks [0,32768) ln(x) [B*N rows];
// [32768,34816) ln(latents) [B*M = 2048 rows];
// [34816,38912) weight convert+transpose f32->bf16 (Wq | Wkv | Wo).
// =====================================================================
__global__ __launch_bounds__(256) void prep_kernel(
    const float* __restrict__ x, const float* __restrict__ lat,
    const float* __restrict__ lnxw, const float* __restrict__ lnxb,
    const float* __restrict__ lnlw, const float* __restrict__ lnlb,
    const float* __restrict__ Wq, const float* __restrict__ Wkv,
    const float* __restrict__ Wo,
    short* __restrict__ xn, short* __restrict__ lnr,
    short* __restrict__ Wqkvt, short* __restrict__ Wot) {
  __shared__ float shbuf[32 * 33];
  int b = blockIdx.x, t = threadIdx.x;
  if (b < 34816) {
    const float *src, *w, *bv; short* dst; int row;
    if (b < 32768) { src = x;   w = lnxw; bv = lnxb; dst = xn;  row = b; }
    else           { src = lat; w = lnlw; bv = lnlb; dst = lnr; row = b - 32768; }
    const float4* x4 = (const float4*)(src + (size_t)row * Dd);
    float4 v = x4[t];
    float s  = v.x + v.y + v.z + v.w;
    float ss = v.x*v.x + v.y*v.y + v.z*v.z + v.w*v.w;
#pragma unroll
    for (int o = 1; o < 64; o <<= 1) {
      s  += __shfl_xor(s,  o, 64);
      ss += __shfl_xor(ss, o, 64);
    }
    int wv = t >> 6;
    if ((t & 63) == 0) { shbuf[wv] = s; shbuf[4 + wv] = ss; }
    __syncthreads();
    float tot  = shbuf[0] + shbuf[1] + shbuf[2] + shbuf[3];
    float tot2 = shbuf[4] + shbuf[5] + shbuf[6] + shbuf[7];
    float mean = tot * (1.0f / Dd);
    float var  = tot2 * (1.0f / Dd) - mean * mean;
    float inv  = rsqrtf(var + 1e-5f);
    float4 wv4 = ((const float4*)w)[t];
    float4 bv4 = ((const float4*)bv)[t];
    short4 o4;
    o4.x = f2bf((v.x - mean) * inv * wv4.x + bv4.x);
    o4.y = f2bf((v.y - mean) * inv * wv4.y + bv4.y);
    o4.z = f2bf((v.z - mean) * inv * wv4.z + bv4.z);
    o4.w = f2bf((v.w - mean) * inv * wv4.w + bv4.w);
    *(short4*)(dst + (size_t)row * Dd + t * 4) = o4;
  } else {
    int tb = b - 34816;
    const float* src; short* dst; int Ncol, bx, by;
    if (tb < 1024)      { src = Wq;  dst = Wqkvt; Ncol = 1024; bx = tb & 31; by = tb >> 5; }
    else if (tb < 3072) { int u = tb - 1024; src = Wkv; dst = Wqkvt + (size_t)1024 * 1024; Ncol = 2048; bx = u & 63; by = u >> 6; }
    else                { int u = tb - 3072; src = Wo;  dst = Wot; Ncol = 1024; bx = u & 31; by = u >> 5; }
    int tx = t & 31, ty = t >> 5;
#pragma unroll
    for (int i = 0; i < 32; i += 8)
      shbuf[(ty + i) * 33 + tx] = src[(size_t)(by * 32 + ty + i) * Ncol + bx * 32 + tx];
    __syncthreads();
#pragma unroll
    for (int i = 0; i < 32; i += 8)
      dst[(size_t)(bx * 32 + ty + i) * 1024 + by * 32 + tx] = f2bf(shbuf[tx * 33 + ty + i]);
  }
}

// =====================================================================
// Merged m97-structure GEMM (one dispatch, 4480 blocks):
//   blocks [0,4096):   A=xn,  Bt=Wkv^T  -> k/v scatter + fused 2D RoPE
//   blocks [4096,4480): A=lnr, Bt=[Wq|Wkv]^T -> q (scaled by 0.125*log2e,
//                       for exp2-softmax) / k_l / v_l at s=N+m
// 128x128 tile, 4 waves, BK=64, ~36KB LDS -> 4 blocks/CU.
// global_load_lds width-16, linear LDS dest + inverse-swizzled source,
// read chunk ^= (row&7); XCD-chunked col-fastest grid swizzle per segment.
// =====================================================================
__global__ __launch_bounds__(256, 4) void gemm_fused_kernel(
    const short* __restrict__ xn, const short* __restrict__ lnr,
    const short* __restrict__ Wkvt, const short* __restrict__ Wqkvt,
    short* __restrict__ qdst, short* __restrict__ kdst, short* __restrict__ vdst) {
  __shared__ __align__(16) short Asm[128 * 64];
  __shared__ __align__(16) short Bsm[128 * 64];
  __shared__ float ctab[1024];
  int t = threadIdx.x;
  int wave = t >> 6, lane = t & 63;
  int wm = (wave >> 1) * 64, wn = (wave & 1) * 64;
  int lr = lane & 15, lg = lane >> 4;
  bool big = (int)blockIdx.x < 4096;
  const short* A  = big ? xn  : lnr;
  const short* Bt = big ? Wkvt : Wqkvt;
  int bid = big ? blockIdx.x : blockIdx.x - 4096;
  int nwg = big ? 4096 : 384;
  int ncp = big ? 16 : 24;
  int cpx = nwg >> 3;
  int swz = (bid & 7) * cpx + (bid >> 3);
  int colp = swz % ncp, rowp = swz / ncp;
  int brow = rowp * 128, bcol = colp * 128;
  if (big) {
#pragma unroll
    for (int i = t; i < 512; i += 256) {
      int pos = i >> 3, f = i & 7;
      float ang = (float)pos * exp2f(-1.6609640474436813f * (float)f);
      ctab[i] = cosf(ang);
      ctab[512 + i] = sinf(ang);
    }
  }
  f32x4 acc[4][4] = {};
  for (int kt = 0; kt < 1024; kt += 64) {
    __syncthreads();
#pragma unroll
    for (int u = 0; u < 4; u++) {
      int cid = t + u * 256;                 // 1024 16B-chunks per operand tile
      int r = cid >> 3, c = cid & 7;
      int cl = c ^ (r & 7);                  // inverse-swizzled global source
      gload16(A + (size_t)(brow + r) * 1024 + kt + cl * 8, Asm + cid * 8);
      gload16(Bt + (size_t)(bcol + r) * 1024 + kt + cl * 8, Bsm + cid * 8);
    }
    __syncthreads();                         // drains vmcnt before barrier
#pragma unroll
    for (int ks = 0; ks < 2; ks++) {
      short8 a[4], b[4];
#pragma unroll
      for (int i = 0; i < 4; i++) {
        int ra = wm + i * 16 + lr;
        a[i] = *(const short8*)(Asm + ra * 64 + (((ks * 4 + lg) ^ (ra & 7)) * 8));
        int rb = wn + i * 16 + lr;
        b[i] = *(const short8*)(Bsm + rb * 64 + (((ks * 4 + lg) ^ (rb & 7)) * 8));
      }
#pragma unroll
      for (int mi = 0; mi < 4; mi++)
#pragma unroll
        for (int ni = 0; ni < 4; ni++)
          acc[mi][ni] = __builtin_amdgcn_mfma_f32_16x16x32_bf16(a[mi], b[ni], acc[mi][ni], 0, 0, 0);
    }
  }
  // ---------------- epilogue ----------------
  int cbase = bcol + wn;                     // wave's 64-col block = one head slice
  if (big) {
    bool kreg = cbase < 1024;
    short* dstp = kreg ? kdst : vdst;
    int h = (cbase & 1023) >> 6;
#pragma unroll
    for (int mi = 0; mi < 4; mi++)
#pragma unroll
      for (int rr = 0; rr < 4; rr++) {
        int row = brow + wm + mi * 16 + lg * 4 + rr;
        int bb = row >> 12, n = row & 4095;
        float v[4];
#pragma unroll
        for (int ni = 0; ni < 4; ni++) v[ni] = acc[mi][ni][rr];
        if (kreg) {                           // fused 2D RoPE on d<32 (ni 0,1)
          int pos = (lr & 8) ? (n & 63) : (n >> 6);
          float cs = ctab[pos * 8 + (lr & 7)];
          float sn = ctab[512 + pos * 8 + (lr & 7)];
          float v0 = v[0], v1 = v[1];
          v[0] = v0 * cs - v1 * sn;
          v[1] = v1 * cs + v0 * sn;
        }
        size_t rb = (((size_t)(bb * Hh + h)) * Ss + n) * HDd;
#pragma unroll
        for (int ni = 0; ni < 4; ni++)
          dstp[rb + ni * 16 + lr] = f2bf(v[ni]);
      }
  } else {
#pragma unroll
    for (int mi = 0; mi < 4; mi++)
#pragma unroll
      for (int rr = 0; rr < 4; rr++) {
        int row = brow + wm + mi * 16 + lg * 4 + rr;
        int bb = row >> 8, m = row & 255;
        float v[4];
#pragma unroll
        for (int ni = 0; ni < 4; ni++) v[ni] = acc[mi][ni][rr];
        if (cbase < 1024) {                  // q, scaled HD^-0.5 * log2(e)
          int h = cbase >> 6;
          size_t rb = (((size_t)(bb * Hh + h)) * Mm + m) * HDd;
#pragma unroll
          for (int ni = 0; ni < 4; ni++)
            qdst[rb + ni * 16 + lr] = f2bf(v[ni] * 0.18033688f);
        } else if (cbase < 2048) {           // k_l at s = N + m
          int h = (cbase - 1024) >> 6;
          size_t rb = (((size_t)(bb * Hh + h)) * Ss + (Nn + m)) * HDd;
#pragma unroll
          for (int ni = 0; ni < 4; ni++)
            kdst[rb + ni * 16 + lr] = f2bf(v[ni]);
        } else {                             // v_l at s = N + m
          int h = (cbase - 2048) >> 6;
          size_t rb = (((size_t)(bb * Hh + h)) * Ss + (Nn + m)) * HDd;
#pragma unroll
          for (int ni = 0; ni < 4; ni++)
            vdst[rb + ni * 16 + lr] = f2bf(v[ni]);
        }
      }
  }
}

// ---------------- out projection: C[2048][1024] fp32 = aout bf16 @ Wo^T ----------------
__global__ __launch_bounds__(256, 4) void gemm_out_kernel(
    const short* __restrict__ A, const short* __restrict__ Bt,
    float* __restrict__ C, int ncp) {
  __shared__ __align__(16) short Asm[128 * 64];
  __shared__ __align__(16) short Bsm[128 * 64];
  int t = threadIdx.x;
  int wave = t >> 6, lane = t & 63;
  int wm = (wave >> 1) * 64, wn = (wave & 1) * 64;
  int lr = lane & 15, lg = lane >> 4;
  int nwg = gridDim.x;
  int cpx = nwg >> 3;
  int swz = (blockIdx.x & 7) * cpx + (blockIdx.x >> 3);
  int colp = swz % ncp, rowp = swz / ncp;
  int brow = rowp * 128, bcol = colp * 128;
  f32x4 acc[4][4] = {};
  for (int kt = 0; kt < 1024; kt += 64) {
    __syncthreads();
#pragma unroll
    for (int u = 0; u < 4; u++) {
      int cid = t + u * 256;
      int r = cid >> 3, c = cid & 7;
      int cl = c ^ (r & 7);
      gload16(A + (size_t)(brow + r) * 1024 + kt + cl * 8, Asm + cid * 8);
      gload16(Bt + (size_t)(bcol + r) * 1024 + kt + cl * 8, Bsm + cid * 8);
    }
    __syncthreads();
#pragma unroll
    for (int ks = 0; ks < 2; ks++) {
      short8 a[4], b[4];
#pragma unroll
      for (int i = 0; i < 4; i++) {
        int ra = wm + i * 16 + lr;
        a[i] = *(const short8*)(Asm + ra * 64 + (((ks * 4 + lg) ^ (ra & 7)) * 8));
        int rb = wn + i * 16 + lr;
        b[i] = *(const short8*)(Bsm + rb * 64 + (((ks * 4 + lg) ^ (rb & 7)) * 8));
      }
#pragma unroll
      for (int mi = 0; mi < 4; mi++)
#pragma unroll
        for (int ni = 0; ni < 4; ni++)
          acc[mi][ni] = __builtin_amdgcn_mfma_f32_16x16x32_bf16(a[mi], b[ni], acc[mi][ni], 0, 0, 0);
    }
  }
#pragma unroll
  for (int mi = 0; mi < 4; mi++)
#pragma unroll
    for (int ni = 0; ni < 4; ni++)
#pragma unroll
      for (int r = 0; r < 4; r++) {
        int row = brow + wm + mi * 16 + lg * 4 + r;
        int col = bcol + wn + ni * 16 + lr;
        C[(size_t)row * 1024 + col] = acc[mi][ni][r];
      }
}

// =====================================================================
// Flash attention, KV-split, NO-MAX exp2-softmax, SWAPPED QK^T.
// q pre-scaled by log2e -> softmax uses exp2f (bare v_exp_f32).
// P^T stays in registers (V key-slot permutation in LDS); O^T partials
// written bf16 [d][q]; fp32 denominators.
// (Round-10 structure: single buffer, 2 barriers/tile. Measured local
// optimum: gload-dbuf, KVBLK=128, reg-dbuf, K-from-L2 all regressed.)
// =====================================================================
__global__ __launch_bounds__(512) void attn_kernel(const short* __restrict__ qb,
                            const short* __restrict__ kb,
                            const short* __restrict__ vb,
                            short* __restrict__ pO,
                            float* __restrict__ pS) {
  __shared__ __align__(16) short Ksm[64 * 64];       // [key][d], chunk^=(key&7)
  __shared__ __align__(16) short Vsm[64 * 64];       // [d][slot], chunk^=(d&7)
  int blk = blockIdx.x;
  int sp = blk & (SPLIT - 1), bh = blk >> 3;
  int t = threadIdx.x, wave = t >> 6, lane = t & 63;
  int lr = lane & 15, lg = lane >> 4;
  int q0 = wave * 32;
  const short* qptr = qb + (size_t)bh * Mm * HDd;
  short8 qf[2][2];
#pragma unroll
  for (int qi = 0; qi < 2; qi++)
#pragma unroll
    for (int ks = 0; ks < 2; ks++)
      qf[qi][ks] = *(const short8*)(qptr + (size_t)(q0 + qi * 16 + lr) * HDd + ks * 32 + lg * 8);
  f32x4 accOT[4][2] = {};                    // [di][qi], O^T: col=q, rows=d
  float psq[2] = {0.0f, 0.0f};               // per-lane denominator partials
  const short* kbase = kb + (size_t)bh * Ss * HDd;
  const short* vbase = vb + (size_t)bh * Ss * HDd;
  int tile0 = (sp * 68) >> 3, tile1 = ((sp + 1) * 68) >> 3;
  for (int tt = tile0; tt < tile1; tt++) {
    int kt = tt * 64;
    __syncthreads();
    {
      int r = t >> 3, c = t & 7;             // 512 threads, one 16B chunk each
      int cl = c ^ (r & 7);
      gload16(kbase + (size_t)(kt + r) * HDd + cl * 8, Ksm + t * 8);
      short8 vv = *(const short8*)(vbase + (size_t)(kt + r) * HDd + c * 8);
      int sc = ((r >> 5) << 2) | ((r >> 2) & 3);   // permuted slot chunk
      int sw = (((r >> 4) & 1) << 2) | (r & 3);    // slot within chunk
#pragma unroll
      for (int e = 0; e < 8; e++) {
        int d = c * 8 + e;
        Vsm[d * 64 + ((sc ^ (d & 7)) * 8) + sw] = vv[e];
      }
    }
    __syncthreads();
    // S^T = K @ Q^T  (swapped operands)
    f32x4 accST[4][2] = {};                  // [ji = k-subtile][qi]
#pragma unroll
    for (int ks = 0; ks < 2; ks++) {
      short8 ka[4];
#pragma unroll
      for (int ji = 0; ji < 4; ji++) {
        int j = ji * 16 + lr;
        int cd = ks * 4 + lg;
        ka[ji] = *(const short8*)(Ksm + j * 64 + ((cd ^ (j & 7)) * 8));
      }
#pragma unroll
      for (int ji = 0; ji < 4; ji++)
#pragma unroll
        for (int qi = 0; qi < 2; qi++)
          accST[ji][qi] = __builtin_amdgcn_mfma_f32_16x16x32_bf16(ka[ji], qf[qi][ks], accST[ji][qi], 0, 0, 0);
    }
    // P^T = 2^(S^T); in-lane denominator partials; pack PV B-frags in-reg
    short8 pb[2][2];                         // [s][qi]
#pragma unroll
    for (int qi = 0; qi < 2; qi++) {
#pragma unroll
      for (int ji = 0; ji < 4; ji++)
#pragma unroll
        for (int r = 0; r < 4; r++) {
          float pv = exp2f(accST[ji][qi][r]);
          accST[ji][qi][r] = pv;
          psq[qi] += pv;
        }
#pragma unroll
      for (int s = 0; s < 2; s++)
#pragma unroll
        for (int r = 0; r < 4; r++) {
          pb[s][qi][r]     = f2bf(accST[2 * s][qi][r]);
          pb[s][qi][4 + r] = f2bf(accST[2 * s + 1][qi][r]);
        }
    }
    // O^T += V^T @ P^T
#pragma unroll
    for (int s = 0; s < 2; s++) {
      short8 va[4];
#pragma unroll
      for (int di = 0; di < 4; di++) {
        int d = di * 16 + lr;
        int ck = s * 4 + lg;
        va[di] = *(const short8*)(Vsm + d * 64 + ((ck ^ (d & 7)) * 8));
      }
#pragma unroll
      for (int di = 0; di < 4; di++)
#pragma unroll
        for (int qi = 0; qi < 2; qi++)
          accOT[di][qi] = __builtin_amdgcn_mfma_f32_16x16x32_bf16(va[di], pb[s][qi], accOT[di][qi], 0, 0, 0);
    }
  }
  // denominator: reduce across the 4 lg-groups
#pragma unroll
  for (int qi = 0; qi < 2; qi++) {
    psq[qi] += __shfl_xor(psq[qi], 16, 64);
    psq[qi] += __shfl_xor(psq[qi], 32, 64);
  }
  // write split partials: pS [q] fp32, pO bf16 transposed [d][q] per block
  size_t base = (size_t)blk * 256;
  if (lane < 16) {
#pragma unroll
    for (int qi = 0; qi < 2; qi++)
      pS[base + q0 + qi * 16 + lr] = psq[qi];
  }
  short* poB = pO + base * 64;               // blk * 16384
#pragma unroll
  for (int di = 0; di < 4; di++)
#pragma unroll
    for (int qi = 0; qi < 2; qi++)
#pragma unroll
      for (int r = 0; r < 4; r++)
        poB[(size_t)(di * 16 + lg * 4 + r) * 256 + q0 + qi * 16 + lr] = f2bf(accOT[di][qi][r]);
}

// ---------------- combine the SPLIT partials ([d][q] bf16, coalesced) ----------------
__global__ void attn_combine(const short* __restrict__ pO, const float* __restrict__ pS,
                             short* __restrict__ ob) {
  int blk = blockIdx.x;                      // 256 = bh*2 + d-half
  int bh = blk >> 1, dh = (blk & 1) << 5;    // 32 d-rows per block
  int q = threadIdx.x;                       // 256 threads = q
  float den = 0.0f;
  float acc[32] = {};
#pragma unroll
  for (int s = 0; s < SPLIT; s++) {
    size_t b2 = (size_t)(bh * SPLIT + s);
    den += pS[b2 * 256 + q];
    const short* po = pO + b2 * 16384 + (size_t)dh * 256;
#pragma unroll
    for (int d = 0; d < 32; d++) acc[d] += bf2f(po[d * 256 + q]);
  }
  float rden = 1.0f / den;
  int b = bh >> 4, h = bh & 15;
  short* dst = ob + ((size_t)(b * Mm + q)) * INNERd + h * HDd + dh;
#pragma unroll
  for (int c = 0; c < 4; c++) {
    short8 o8;
#pragma unroll
    for (int e = 0; e < 8; e++) o8[e] = f2bf(acc[c * 8 + e] * rden);
    *(short8*)(dst + c * 8) = o8;
  }
}

extern "C" void kernel_launch(void* const* d_in, const int* in_sizes, int n_in,
                              void* d_out, int out_size, void* d_ws, size_t ws_size,
                              hipStream_t stream) {
  const float* x    = (const float*)d_in[0];
  const float* lat  = (const float*)d_in[1];
  const float* lnxw = (const float*)d_in[2];
  const float* lnxb = (const float*)d_in[3];
  const float* lnlw = (const float*)d_in[4];
  const float* lnlb = (const float*)d_in[5];
  const float* Wq   = (const float*)d_in[6];
  const float* Wkv  = (const float*)d_in[7];
  const float* Wo   = (const float*)d_in[8];
  char* w = (char*)d_ws;
  const size_t MB = 1048576;
  short* Wqkvt = (short*)(w + 0 * MB);     // 6 MB: rows 0-1023 = Wq^T, 1024-3071 = Wkv^T
  short* Wot   = (short*)(w + 6 * MB);     // 2 MB
  short* xn    = (short*)(w + 8 * MB);     // 64 MB (reused as pO by attn)
  short* lnr   = (short*)(w + 72 * MB);    // 4 MB (reused as pS by attn)
  short* qbuf  = (short*)(w + 76 * MB);    // 4 MB
  short* kbuf  = (short*)(w + 80 * MB);    // 68 MB
  short* vbuf  = (short*)(w + 148 * MB);   // 68 MB
  short* aout  = (short*)(w + 216 * MB);   // 4 MB
  short* pO    = (short*)(w + 8 * MB);     // 32 MB bf16, aliases xn (dead by attn time)
  float* pS    = (float*)(w + 72 * MB);    // 1 MB, aliases lnr (dead by attn time)

  // fused prep: ln(x) [32768], ln(latents) [2048], weight converts [4096]
  prep_kernel<<<dim3(38912), dim3(256), 0, stream>>>(
      x, lat, lnxw, lnxb, lnlw, lnlb, Wq, Wkv, Wo, xn, lnr, Wqkvt, Wot);
  // merged GEMM: kv_x (+RoPE) and q+kv_l in one dispatch
  gemm_fused_kernel<<<dim3(4480), dim3(256), 0, stream>>>(
      xn, lnr, Wqkvt + (size_t)1024 * 1024, Wqkvt, qbuf, kbuf, vbuf);
  // flash attention with KV-split 8 + combine
  attn_kernel<<<dim3(Bb * Hh * SPLIT), dim3(512), 0, stream>>>(qbuf, kbuf, vbuf, pO, pS);
  attn_combine<<<dim3(256), dim3(256), 0, stream>>>(pO, pS, aout);
  // out = aout @ Wo (fp32).  grid: 16 rowp x 8 colp = 128
  gemm_out_kernel<<<dim3(128), dim3(256), 0, stream>>>(aout, Wot, (float*)d_out, 8);
}